// Round 1
// baseline (708.619 us; speedup 1.0000x reference)
//
#include <hip/hip_runtime.h>
#include <hip/hip_bf16.h>

// Problem constants (fixed by reference)
#define NCH   4096   // children
#define NPAR  128    // parents
#define KD    16
#define CHUNK 128                 // children per block in pool_pairs
#define NCHUNK (NCH / CHUNK)      // 32

typedef __attribute__((ext_vector_type(4))) float f4;
typedef __attribute__((ext_vector_type(8))) short bh8;
typedef __attribute__((ext_vector_type(4))) int   i4;

static __device__ __forceinline__ unsigned pk2(float a, float b) {
  float2 t; t.x = a; t.y = b;
  union { __hip_bfloat162 h2; unsigned u; } cv;
  cv.h2 = __float22bfloat162_rn(t);   // .x in low 16 bits
  return cv.u;
}

// ---------------------------------------------------------------------------
// Phase 1: Lambda_n = inv(Sigma_n), 16x16 SPD Gauss-Jordan (no pivoting; diag>=1).
// Output stored as bf16 row-major (16x16) -> phase 2 loads MFMA fragments
// DIRECTLY from it (lane(q,t) <- row t, cols 8q..8q+7 is one contiguous i4).
// ---------------------------------------------------------------------------
__global__ __launch_bounds__(256) void invert_sigma(const float* __restrict__ sig,
                                                    unsigned short* __restrict__ lam) {
  __shared__ float A[16][17];
  __shared__ float B[16][17];
  const int n = blockIdx.x;
  const int t = threadIdx.x, i = t >> 4, j = t & 15;
  A[i][j] = sig[(size_t)n * 256 + t];
  B[i][j] = (i == j) ? 1.0f : 0.0f;
  __syncthreads();
  for (int k = 0; k < 16; ++k) {
    const float ip  = 1.0f / A[k][k];
    const float akj = A[k][j] * ip;
    const float bkj = B[k][j] * ip;
    const float f   = A[i][k];
    __syncthreads();
    if (i == k) { A[i][j] = akj;      B[i][j] = bkj; }
    else        { A[i][j] -= f * akj; B[i][j] -= f * bkj; }
    __syncthreads();
  }
  __hip_bfloat16 h = __float2bfloat16(B[i][j]);
  lam[(size_t)n * 256 + t] = *reinterpret_cast<unsigned short*>(&h);
}

// ---------------------------------------------------------------------------
// Phase 2: per pair (m,n):  Ct = Omega Lambda Omega^T  via 2 bf16 MFMAs.
//
// NO LDS STAGING: the A-fragment layout (lane(q,t) holds row t, cols 8q..8q+7,
// quads 0,1 live / quads 2,3 zero) is loaded straight from global memory:
//   Omega: two f4 loads at transport[... + t*16 + 8q(+4)], cvt_pk -> bf16.
//   Lambda: one i4 load (already bf16 row-major) at lam[... + t*16 + 8q].
// Both are fully coalesced (32 active lanes cover the whole contiguous matrix).
// This removes the per-iteration LDS write->read roundtrip (~130cy lgkm RAW)
// that was on the serial chain, plus 4 DS ops and the repack cndmasks.
//
//   MFMA1: P = A(Lambda) * B(Omega-frag => Omega^T).
//   repack P (C-layout) -> B-layout with 4 bpermutes (q>=2 rows multiply the
//   zero cols 16..31 of the Omega A-operand, so no masking needed).
//   MFMA2: Ct = A(Omega) * B(P) = Omega Lambda Omega^T.
//   mu_t[t] = dot(Omega row t (full f32), mu) + xor-shuffle reduce over quads.
//   accLp[r] += w * Ct[r];  accIn[r] += (w*mu_t[t]) * Ct[r].
//
// 2-slot register pipeline (named regs, static indices) for global prefetch;
// inactive lanes (q>=2) are zero-initialized once and never loaded into, so
// all dead operand halves are exact 0.0f (no Inf/NaN garbage into MFMA).
// ---------------------------------------------------------------------------
__global__ __launch_bounds__(256) void pool_pairs(
    const float* __restrict__ transport,
    const unsigned short* __restrict__ lam,
    const float* __restrict__ mu,
    const float* __restrict__ weights,
    float* __restrict__ Lp,     // (128,16,16) accumulated via atomics (pre-zeroed)
    float* __restrict__ info) { // (128,16)
  __shared__ float sMu[CHUNK * 16];
  __shared__ float sW[CHUNK];
  __shared__ float sRedLp[4][256];
  __shared__ float sRedIn[4][16];

  const int bx = blockIdx.x;
  const int m  = bx & (NPAR - 1);     // consecutive blocks share the n-chunk -> L2 reuse of Lambda/mu
  const int c  = bx >> 7;
  const int tid = threadIdx.x;
  const int w = tid >> 6;             // wave id
  const int L = tid & 63;             // lane
  const int q = L >> 4;               // quad
  const int t = L & 15;

  // Prestage chunk mu (CHUNK*16 f32) and weights column for this m.
  #pragma unroll
  for (int r = 0; r < (CHUNK * 16) / 256; ++r) {
    const int idx = r * 256 + tid;
    sMu[idx] = mu[(size_t)c * CHUNK * 16 + idx];
  }
  if (tid < CHUNK) sW[tid] = weights[(size_t)(c * CHUNK + tid) * NPAR + m];
  __syncthreads();

  const int PER_WAVE = CHUNK / 4;                 // 32 pairs per wave
  const int n0 = c * CHUNK + w * PER_WAVE;        // global child base for this wave

  const int  foff = t * 16 + q * 8;               // element offset of fragment within a 16x16 matrix
  const bool act  = (q < 2);                      // only quads 0,1 carry fragment data

  const float*          tb = transport + ((size_t)m * NCH + n0) * 256 + foff;
  const unsigned short* lb = lam + (size_t)n0 * 256 + foff;
  const float*          muq = sMu + (q & 1) * 8;

  f4 accLp = {0.f, 0.f, 0.f, 0.f};
  f4 accIn = {0.f, 0.f, 0.f, 0.f};
  const f4 zf = {0.f, 0.f, 0.f, 0.f};

  // 2-slot pipeline registers. q>=2 lanes keep exact zeros forever.
  f4 oA0 = zf, oA1 = zf, oB0 = zf, oB1 = zf;
  i4 lA = {0, 0, 0, 0}, lB = {0, 0, 0, 0};
  if (act) {
    oA0 = *(const f4*)(tb + 0);
    oA1 = *(const f4*)(tb + 4);
    lA  = *(const i4*)(lb + 0);
    oB0 = *(const f4*)(tb + 256);
    oB1 = *(const f4*)(tb + 260);
    lB  = *(const i4*)(lb + 256);
  }

  const int srcA = t + (q & 1) * 32;   // repack bpermute source (loop-invariant)

  for (int it = 0; it < PER_WAVE; it += 2) {
    // ================= body A (pair it) =================
    {
      const int nloc = w * PER_WAVE + it;
      union { i4 i; bh8 h; } co, cl, cp;
      co.i.x = (int)pk2(oA0.x, oA0.y);
      co.i.y = (int)pk2(oA0.z, oA0.w);
      co.i.z = (int)pk2(oA1.x, oA1.y);
      co.i.w = (int)pk2(oA1.z, oA1.w);
      cl.i = lA;

      // mu_t[t] from full-f32 Omega registers
      const float* mv = muq + nloc * 16;
      const f4 m0 = *(const f4*)(mv);
      const f4 m1 = *(const f4*)(mv + 4);
      float p = oA0.x * m0.x + oA0.y * m0.y + oA0.z * m0.z + oA0.w * m0.w +
                oA1.x * m1.x + oA1.y * m1.y + oA1.z * m1.z + oA1.w * m1.w;

      // prefetch pair it+2 into slot A (regs dead after the cvt/dot above)
      const int ia = (it + 2 < PER_WAVE) ? it + 2 : it;
      if (act) {
        oA0 = *(const f4*)(tb + (size_t)ia * 256);
        oA1 = *(const f4*)(tb + (size_t)ia * 256 + 4);
        lA  = *(const i4*)(lb + (size_t)ia * 256);
      }

      p += __shfl_xor(p, 16, 64);
      p += __shfl_xor(p, 32, 64);      // p = mu_t[t] in every lane

      // MFMA1: P = Lambda * Omega^T
      f4 P = __builtin_amdgcn_mfma_f32_16x16x32_bf16(cl.h, co.h, zf, 0, 0, 0);
      const unsigned pLo = pk2(P.x, P.y);
      const unsigned pHi = pk2(P.z, P.w);
      cp.i.x = __shfl((int)pLo, srcA, 64);
      cp.i.y = __shfl((int)pHi, srcA, 64);
      cp.i.z = __shfl((int)pLo, srcA + 16, 64);
      cp.i.w = __shfl((int)pHi, srcA + 16, 64);

      // MFMA2: Ct = Omega * P
      f4 Ct = __builtin_amdgcn_mfma_f32_16x16x32_bf16(co.h, cp.h, zf, 0, 0, 0);

      const float wv  = sW[nloc];
      const float wmu = wv * p;
      accLp.x += wv * Ct.x;  accIn.x += wmu * Ct.x;
      accLp.y += wv * Ct.y;  accIn.y += wmu * Ct.y;
      accLp.z += wv * Ct.z;  accIn.z += wmu * Ct.z;
      accLp.w += wv * Ct.w;  accIn.w += wmu * Ct.w;
    }
    // ================= body B (pair it+1) =================
    {
      const int nloc = w * PER_WAVE + it + 1;
      union { i4 i; bh8 h; } co, cl, cp;
      co.i.x = (int)pk2(oB0.x, oB0.y);
      co.i.y = (int)pk2(oB0.z, oB0.w);
      co.i.z = (int)pk2(oB1.x, oB1.y);
      co.i.w = (int)pk2(oB1.z, oB1.w);
      cl.i = lB;

      const float* mv = muq + nloc * 16;
      const f4 m0 = *(const f4*)(mv);
      const f4 m1 = *(const f4*)(mv + 4);
      float p = oB0.x * m0.x + oB0.y * m0.y + oB0.z * m0.z + oB0.w * m0.w +
                oB1.x * m1.x + oB1.y * m1.y + oB1.z * m1.z + oB1.w * m1.w;

      const int ib = (it + 3 < PER_WAVE) ? it + 3 : it + 1;
      if (act) {
        oB0 = *(const f4*)(tb + (size_t)ib * 256);
        oB1 = *(const f4*)(tb + (size_t)ib * 256 + 4);
        lB  = *(const i4*)(lb + (size_t)ib * 256);
      }

      p += __shfl_xor(p, 16, 64);
      p += __shfl_xor(p, 32, 64);

      f4 P = __builtin_amdgcn_mfma_f32_16x16x32_bf16(cl.h, co.h, zf, 0, 0, 0);
      const unsigned pLo = pk2(P.x, P.y);
      const unsigned pHi = pk2(P.z, P.w);
      cp.i.x = __shfl((int)pLo, srcA, 64);
      cp.i.y = __shfl((int)pHi, srcA, 64);
      cp.i.z = __shfl((int)pLo, srcA + 16, 64);
      cp.i.w = __shfl((int)pHi, srcA + 16, 64);

      f4 Ct = __builtin_amdgcn_mfma_f32_16x16x32_bf16(co.h, cp.h, zf, 0, 0, 0);

      const float wv  = sW[nloc];
      const float wmu = wv * p;
      accLp.x += wv * Ct.x;  accIn.x += wmu * Ct.x;
      accLp.y += wv * Ct.y;  accIn.y += wmu * Ct.y;
      accLp.z += wv * Ct.z;  accIn.z += wmu * Ct.z;
      accLp.w += wv * Ct.w;  accIn.w += wmu * Ct.w;
    }
  }

  // Per-wave partials -> LDS
  sRedLp[w][(q * 4 + 0) * 16 + t] = accLp.x;
  sRedLp[w][(q * 4 + 1) * 16 + t] = accLp.y;
  sRedLp[w][(q * 4 + 2) * 16 + t] = accLp.z;
  sRedLp[w][(q * 4 + 3) * 16 + t] = accLp.w;

  float i0 = accIn.x, i1 = accIn.y, i2 = accIn.z, i3 = accIn.w;
  #pragma unroll
  for (int off = 1; off < 16; off <<= 1) {
    i0 += __shfl_xor(i0, off, 64);
    i1 += __shfl_xor(i1, off, 64);
    i2 += __shfl_xor(i2, off, 64);
    i3 += __shfl_xor(i3, off, 64);
  }
  if (t == 0) {
    sRedIn[w][q * 4 + 0] = i0;
    sRedIn[w][q * 4 + 1] = i1;
    sRedIn[w][q * 4 + 2] = i2;
    sRedIn[w][q * 4 + 3] = i3;
  }
  __syncthreads();

  const float s = sRedLp[0][tid] + sRedLp[1][tid] + sRedLp[2][tid] + sRedLp[3][tid];
  atomicAdd(&Lp[(size_t)m * 256 + tid], s);
  if (tid < 16) {
    const float si = sRedIn[0][tid] + sRedIn[1][tid] + sRedIn[2][tid] + sRedIn[3][tid];
    atomicAdd(&info[(size_t)m * 16 + tid], si);
  }
}

// ---------------------------------------------------------------------------
// Phase 3: symmetrize Lp, invert (eigenclamp at 1e-4 is a provable no-op:
// Lp eigenvalues are O(50..5000)), mu = Sigma_pooled * info.
// ---------------------------------------------------------------------------
__global__ __launch_bounds__(256) void finalize(const float* __restrict__ Lp,
                                                const float* __restrict__ info,
                                                float* __restrict__ out) {
  __shared__ float A[16][17];
  __shared__ float B[16][17];
  __shared__ float infoS[16];
  const int m = blockIdx.x;
  const int tid = threadIdx.x, i = tid >> 4, j = tid & 15;
  const float* Lm = Lp + (size_t)m * 256;
  A[i][j] = 0.5f * (Lm[i * 16 + j] + Lm[j * 16 + i]);
  B[i][j] = (i == j) ? 1.0f : 0.0f;
  if (tid < 16) infoS[tid] = info[(size_t)m * 16 + tid];
  __syncthreads();
  for (int k = 0; k < 16; ++k) {
    const float ip  = 1.0f / A[k][k];
    const float akj = A[k][j] * ip;
    const float bkj = B[k][j] * ip;
    const float f   = A[i][k];
    __syncthreads();
    if (i == k) { A[i][j] = akj;      B[i][j] = bkj; }
    else        { A[i][j] -= f * akj; B[i][j] -= f * bkj; }
    __syncthreads();
  }
  // sigma_pooled
  out[(size_t)KD * NPAR + (size_t)m * 256 + tid] = B[i][j];
  // mu_pooled
  if (tid < 16) {
    float s = 0.f;
    #pragma unroll
    for (int jj = 0; jj < 16; ++jj) s += B[tid][jj] * infoS[jj];
    out[(size_t)m * 16 + tid] = s;
  }
}

// ---------------------------------------------------------------------------
extern "C" void kernel_launch(void* const* d_in, const int* in_sizes, int n_in,
                              void* d_out, int out_size, void* d_ws, size_t ws_size,
                              hipStream_t stream) {
  const float* mu_children    = (const float*)d_in[0];  // (N,K)
  const float* sigma_children = (const float*)d_in[1];  // (N,K,K)
  const float* weights        = (const float*)d_in[2];  // (N,M)
  const float* transport      = (const float*)d_in[3];  // (M,N,K,K)
  float* out = (float*)d_out;                           // mu (M,K) ++ sigma (M,K,K)

  // ws layout: [0,2MB) Lambda bf16; then Lp f32 (128*256); then info f32 (128*16)
  unsigned short* lam = (unsigned short*)d_ws;
  float* Lp   = (float*)((char*)d_ws + (size_t)NCH * 256 * sizeof(unsigned short));
  float* info = Lp + (size_t)NPAR * 256;

  hipMemsetAsync(Lp, 0, (size_t)(NPAR * 256 + NPAR * 16) * sizeof(float), stream);
  invert_sigma<<<NCH, 256, 0, stream>>>(sigma_children, lam);
  pool_pairs<<<NPAR * NCHUNK, 256, 0, stream>>>(transport, lam, mu_children, weights, Lp, info);
  finalize<<<NPAR, 256, 0, stream>>>(Lp, info, out);
}